// Round 2
// baseline (2732.593 us; speedup 1.0000x reference)
//
#include <hip/hip_runtime.h>
#include <hip/hip_bf16.h>
#include <math.h>

// ---------------- problem constants ----------------
#define BIMG   4
#define CIN    512
#define MID    512
#define HF     50
#define WF     50
#define PIX    2500          // HF*WF
#define MTOT   10000         // BIMG*PIX
#define ANC    9
#define NLOC   22500         // PIX*ANC
#define NPRE   3000
#define NPOST  300
#define WORDS  47            // ceil(3000/64)
#define ROWPAD 3008
#define WSTRIDE 48           // padded words per NMS row

// d_out layout (floats): rois, rois_idx, anchors, loc, bf_pred
#define ROIS_OFF 0
#define IDX_OFF  4800
#define ANC_OFF  6000
#define LOC_OFF  96000
#define BF_OFF   456000

// ws layout (byte offsets). raw (f64) aliases Wt (dead after conv3x3).
#define WS_WT     0UL                      // 4608*512 f32   = 9,437,184 B (raw f64 5,120,000 aliased)
#define WS_W1T    9437184UL                // 512*64 f32     =   131,072 B
#define WS_FEAT   9568256UL                // 10000*512 f32  = 20,480,000 B
#define WS_SCORE  30048256UL               // 90000 f64      =    720,000 B
#define WS_BOXD   30768256UL               // 90000*4 f64    =  2,880,000 B
#define WS_SBD    33648256UL               // 4*3000*4 f64   =    384,000 B
#define WS_M      34032256UL               // 4*3008*48 u64  =  4,620,288 B
// total = 38,652,544 B (~36.9 MiB)

// ---------------- kernel 0: weight prep ----------------
__global__ __launch_bounds__(256) void prep_kernel(
    const float* __restrict__ conv_w, const float* __restrict__ loc_w,
    const float* __restrict__ bf_w, float* __restrict__ Wt, float* __restrict__ W1t) {
  int o = blockIdx.x * 256 + threadIdx.x;
  if (o < 4608 * 512) {
    int co  = o & 511;
    int k   = o >> 9;          // tap*512 + c
    int c   = k & 511;
    int tap = k >> 9;
    Wt[o] = conv_w[(co * 512 + c) * 9 + tap];
  } else {
    int o2 = o - 4608 * 512;
    if (o2 < 512 * 64) {
      int co = o2 & 63;
      int c  = o2 >> 6;
      float v = 0.0f;
      if (co < 36)      v = loc_w[co * 512 + c];
      else if (co < 54) v = bf_w[(co - 36) * 512 + c];
      W1t[o2] = v;
    }
  }
}

// ---------------- kernel 1: 3x3 conv + bias + relu (f64 accumulate) ----------------
// feat stored NHWC f32: feat[q*512 + co] = (float)relu(acc_f64 + bias)
__global__ __launch_bounds__(256) void conv3x3_kernel(
    const float* __restrict__ in, const float* __restrict__ Wt,
    const float* __restrict__ bias, float* __restrict__ feat) {
  __shared__ float As[16][132];
  __shared__ float Bs[16][68];
  int tid = threadIdx.x;
  int q0  = blockIdx.x * 128;
  int co0 = blockIdx.y * 64;
  int tx = tid & 15, ty = tid >> 4;

  int pix = tid & 127;
  int kk0 = tid >> 7;           // 0 or 1
  int q   = q0 + pix;
  bool inimg = q < MTOT;
  int qq = inimg ? q : 0;
  int b  = qq / PIX;
  int r  = qq - b * PIX;
  int y  = r / WF;
  int x  = r - y * WF;
  const float* inb = in + (size_t)b * (CIN * PIX);

  double acc[8][4];
#pragma unroll
  for (int i = 0; i < 8; ++i)
#pragma unroll
    for (int j = 0; j < 4; ++j) acc[i][j] = 0.0;

  for (int kb = 0; kb < 288; ++kb) {
    int tap = kb >> 5;
    int c0  = (kb & 31) << 4;
    int dy  = tap / 3 - 1;
    int dx  = tap - (tap / 3) * 3 - 1;
    int iy  = y + dy, ix = x + dx;
    bool ok = inimg && ((unsigned)iy < (unsigned)HF) && ((unsigned)ix < (unsigned)WF);
    int base = (c0 + kk0) * PIX + iy * WF + ix;
#pragma unroll
    for (int k = 0; k < 8; ++k) {
      float v = ok ? inb[base + k * 2 * PIX] : 0.0f;
      As[kk0 + k * 2][pix] = v;
    }
    const float* wb = Wt + (size_t)(kb * 16) * 512 + co0;
#pragma unroll
    for (int k = 0; k < 4; ++k) {
      int L = tid + k * 256;
      int kk = L >> 6, co = L & 63;
      Bs[kk][co] = wb[kk * 512 + co];
    }
    __syncthreads();
#pragma unroll
    for (int kk = 0; kk < 16; ++kk) {
      float a0[8], b0[4];
      *(float4*)&a0[0] = *(const float4*)&As[kk][ty * 8];
      *(float4*)&a0[4] = *(const float4*)&As[kk][ty * 8 + 4];
      *(float4*)&b0[0] = *(const float4*)&Bs[kk][tx * 4];
      double ad[8], bd[4];
#pragma unroll
      for (int i = 0; i < 8; ++i) ad[i] = (double)a0[i];
#pragma unroll
      for (int j = 0; j < 4; ++j) bd[j] = (double)b0[j];
#pragma unroll
      for (int i = 0; i < 8; ++i)
#pragma unroll
        for (int j = 0; j < 4; ++j) acc[i][j] = fma(ad[i], bd[j], acc[i][j]);
    }
    __syncthreads();
  }
  float4 bsv = *(const float4*)&bias[co0 + tx * 4];
  double bd4[4] = {(double)bsv.x, (double)bsv.y, (double)bsv.z, (double)bsv.w};
#pragma unroll
  for (int i = 0; i < 8; ++i) {
    int qo = q0 + ty * 8 + i;
    if (qo < MTOT) {
      float4 o;
      o.x = (float)fmax(acc[i][0] + bd4[0], 0.0);
      o.y = (float)fmax(acc[i][1] + bd4[1], 0.0);
      o.z = (float)fmax(acc[i][2] + bd4[2], 0.0);
      o.w = (float)fmax(acc[i][3] + bd4[3], 0.0);
      *(float4*)&feat[(size_t)qo * 512 + co0 + tx * 4] = o;
    }
  }
}

// ---------------- kernel 2: fused 1x1 heads, f64 accumulate, f64 raw output ----------------
__global__ __launch_bounds__(256) void conv1x1_kernel(
    const float* __restrict__ feat, const float* __restrict__ W1t,
    const float* __restrict__ locb, const float* __restrict__ bfb,
    double* __restrict__ rawd) {
  __shared__ float As[16][132];
  __shared__ float Bs[16][68];
  int tid = threadIdx.x;
  int q0  = blockIdx.x * 128;
  int tx = tid & 15, ty = tid >> 4;
  int pixL = tid >> 1;
  int ch   = (tid & 1) * 8;
  int qL   = q0 + pixL;
  bool okL = qL < MTOT;

  double acc[8][4];
#pragma unroll
  for (int i = 0; i < 8; ++i)
#pragma unroll
    for (int j = 0; j < 4; ++j) acc[i][j] = 0.0;

  for (int kb = 0; kb < 32; ++kb) {
    int c0 = kb * 16;
    float4 f0 = make_float4(0, 0, 0, 0), f1 = make_float4(0, 0, 0, 0);
    if (okL) {
      const float* fp = &feat[(size_t)qL * 512 + c0 + ch];
      f0 = *(const float4*)fp;
      f1 = *(const float4*)(fp + 4);
    }
    As[ch + 0][pixL] = f0.x; As[ch + 1][pixL] = f0.y;
    As[ch + 2][pixL] = f0.z; As[ch + 3][pixL] = f0.w;
    As[ch + 4][pixL] = f1.x; As[ch + 5][pixL] = f1.y;
    As[ch + 6][pixL] = f1.z; As[ch + 7][pixL] = f1.w;
#pragma unroll
    for (int k = 0; k < 4; ++k) {
      int L = tid + k * 256;
      int kk = L >> 6, co = L & 63;
      Bs[kk][co] = W1t[(c0 + kk) * 64 + co];
    }
    __syncthreads();
#pragma unroll
    for (int kk = 0; kk < 16; ++kk) {
      float a0[8], b0[4];
      *(float4*)&a0[0] = *(const float4*)&As[kk][ty * 8];
      *(float4*)&a0[4] = *(const float4*)&As[kk][ty * 8 + 4];
      *(float4*)&b0[0] = *(const float4*)&Bs[kk][tx * 4];
      double ad[8], bd[4];
#pragma unroll
      for (int i = 0; i < 8; ++i) ad[i] = (double)a0[i];
#pragma unroll
      for (int j = 0; j < 4; ++j) bd[j] = (double)b0[j];
#pragma unroll
      for (int i = 0; i < 8; ++i)
#pragma unroll
        for (int j = 0; j < 4; ++j) acc[i][j] = fma(ad[i], bd[j], acc[i][j]);
    }
    __syncthreads();
  }
  double bs[4];
#pragma unroll
  for (int j = 0; j < 4; ++j) {
    int co = tx * 4 + j;
    bs[j] = (co < 36) ? (double)locb[co] : ((co < 54) ? (double)bfb[co - 36] : 0.0);
  }
#pragma unroll
  for (int i = 0; i < 8; ++i) {
    int qo = q0 + ty * 8 + i;
    if (qo < MTOT) {
      double* rp = &rawd[(size_t)qo * 64 + tx * 4];
      rp[0] = acc[i][0] + bs[0];
      rp[1] = acc[i][1] + bs[1];
      rp[2] = acc[i][2] + bs[2];
      rp[3] = acc[i][3] + bs[3];
    }
  }
}

// ---------------- kernel 3: epilogue — f64 softmax/decode/clip, score=d (f64) ----------------
__global__ __launch_bounds__(256) void epilogue_kernel(
    const double* __restrict__ rawd, float* __restrict__ d_out,
    double* __restrict__ boxd, double* __restrict__ score,
    const int* __restrict__ imh, const int* __restrict__ imw) {
  int idx = blockIdx.x * 256 + threadIdx.x;
  if (idx >= BIMG * NLOC) return;
  int b = idx / NLOC;
  int i = idx - b * NLOC;
  int p = i / ANC;
  int a = i - p * ANC;
  int y = p / WF;
  int x = p - y * WF;
  int q = b * PIX + p;

  // loc (raw regression output)
  double l0d = rawd[(size_t)q * 64 + a * 4 + 0];
  double l1d = rawd[(size_t)q * 64 + a * 4 + 1];
  double l2d = rawd[(size_t)q * 64 + a * 4 + 2];
  double l3d = rawd[(size_t)q * 64 + a * 4 + 3];
  float4 lo = make_float4((float)l0d, (float)l1d, (float)l2d, (float)l3d);
  *(float4*)&d_out[LOC_OFF + (size_t)idx * 4] = lo;

  // softmax over 2 logits (f64)
  double g0 = rawd[(size_t)q * 64 + 36 + a * 2];
  double g1 = rawd[(size_t)q * 64 + 37 + a * 2];
  double m  = fmax(g0, g1);
  double e0 = exp(g0 - m), e1 = exp(g1 - m);
  double s  = e0 + e1;
  double p0 = e0 / s, p1 = e1 / s;
  *(float2*)&d_out[BF_OFF + (size_t)idx * 2] = make_float2((float)p0, (float)p1);

  // anchor (f64)
  int ridx = a / 3, sidx = a - ridx * 3;
  double ratio = (ridx == 0) ? 0.5 : ((ridx == 1) ? 1.0 : 2.0);
  double scale = (sidx == 0) ? 8.0 : ((sidx == 1) ? 16.0 : 32.0);
  double hs = 16.0 * scale * sqrt(ratio);
  double ws = 16.0 * scale * sqrt(1.0 / ratio);
  double sy = (double)(y * 16), sx = (double)(x * 16);
  double a0 = sy + (8.0 - hs * 0.5);
  double a1 = sx + (8.0 - ws * 0.5);
  double a2 = sy + (8.0 + hs * 0.5);
  double a3 = sx + (8.0 + ws * 0.5);
  if (b == 0) {
    *(float4*)&d_out[ANC_OFF + (size_t)i * 4] =
        make_float4((float)a0, (float)a1, (float)a2, (float)a3);
  }

  // decode + clip (f64)
  double ah = a2 - a0, aw = a3 - a1;
  double acy = a0 + 0.5 * ah, acx = a1 + 0.5 * aw;
  double cy = l0d * ah + acy;
  double cx = l1d * aw + acx;
  double hh = exp(l2d) * ah;
  double ww = exp(l3d) * aw;
  double ihf = (double)imh[0], iwf = (double)imw[0];
  double b0 = fmin(fmax(cy - 0.5 * hh, 0.0), ihf);
  double b1 = fmin(fmax(cx - 0.5 * ww, 0.0), iwf);
  double b2 = fmin(fmax(cy + 0.5 * hh, 0.0), ihf);
  double b3 = fmin(fmax(cx + 0.5 * ww, 0.0), iwf);
  double* bp = &boxd[(size_t)idx * 4];
  bp[0] = b0; bp[1] = b1; bp[2] = b2; bp[3] = b3;

  bool valid = (b2 - b0 >= 16.0) && (b3 - b1 >= 16.0);
  // ordering key: p1 is a strictly monotone f64 function of d = g1-g0;
  // sorting by d (desc, idx-asc ties) == np argsort(-p1) stable.
  score[idx] = valid ? (g1 - g0) : -INFINITY;
}

// ---------------- kernel 4: exact top-3000 by rank counting (f64 scores) ----------------
__global__ __launch_bounds__(256) void select_kernel(
    const double* __restrict__ score, const double* __restrict__ boxd,
    double* __restrict__ sbd) {
  __shared__ double kt[256];
  int b = blockIdx.y;
  int i = blockIdx.x * 256 + threadIdx.x;
  bool act = i < NLOC;
  double myd = act ? score[(size_t)b * NLOC + i] : -INFINITY;
  int cnt = 0;
  for (int t = 0; t < 88; ++t) {
    int j0 = t * 256;
    int j = j0 + threadIdx.x;
    kt[threadIdx.x] = (j < NLOC) ? score[(size_t)b * NLOC + j] : -INFINITY;
    __syncthreads();
#pragma unroll 4
    for (int jj = 0; jj < 256; ++jj) {
      double dj = kt[jj];
      int jidx = j0 + jj;
      // better-ranked than i: higher score, or equal score with lower index.
      // padding (jidx>=NLOC) has -inf score and jidx > any real myi -> never counts.
      cnt += ((dj > myd) || (dj == myd && jidx < i)) ? 1 : 0;
    }
    __syncthreads();
  }
  if (act && cnt < NPRE) {
    const double* bx = &boxd[((size_t)b * NLOC + i) * 4];
    double* dp = &sbd[((size_t)b * NPRE + cnt) * 4];
    dp[0] = bx[0]; dp[1] = bx[1]; dp[2] = bx[2]; dp[3] = bx[3];
  }
}

// ---------------- kernel 5: NMS suppression bitmask matrix (f64 IoU) ----------------
__global__ __launch_bounds__(64) void nmsmask_kernel(
    const double* __restrict__ sbd, unsigned long long* __restrict__ M) {
  __shared__ double cb[64][4];
  int b = blockIdx.z;
  int jw = blockIdx.y;                 // column word 0..46
  int i  = blockIdx.x * 64 + threadIdx.x;
  int j  = jw * 64 + threadIdx.x;
  double j0 = 0, j1 = 0, j2 = 0, j3 = 0;
  if (j < NPRE) {
    const double* bp = &sbd[((size_t)b * NPRE + j) * 4];
    j0 = bp[0]; j1 = bp[1]; j2 = bp[2]; j3 = bp[3];
  }
  cb[threadIdx.x][0] = j0; cb[threadIdx.x][1] = j1;
  cb[threadIdx.x][2] = j2; cb[threadIdx.x][3] = j3;
  __syncthreads();
  if (i >= NPRE) return;
  const double* bp = &sbd[((size_t)b * NPRE + i) * 4];
  double i0 = bp[0], i1 = bp[1], i2 = bp[2], i3 = bp[3];
  double ai = (i2 - i0) * (i3 - i1);
  unsigned long long mask = 0ull;
#pragma unroll 4
  for (int t = 0; t < 64; ++t) {
    double aj = (cb[t][2] - cb[t][0]) * (cb[t][3] - cb[t][1]);
    double h = fmax(fmin(i2, cb[t][2]) - fmax(i0, cb[t][0]), 0.0);
    double w = fmax(fmin(i3, cb[t][3]) - fmax(i1, cb[t][1]), 0.0);
    double inter = h * w;
    double iou = inter / (ai + aj - inter + 1e-9);
    mask |= ((iou > 0.7) ? 1ull : 0ull) << t;
  }
  M[((size_t)b * ROWPAD + i) * WSTRIDE + jw] = mask;
}

// ---------------- kernel 6: sequential NMS scan (1 wave / image) ----------------
__global__ __launch_bounds__(64) void nms_scan_kernel(
    const double* __restrict__ sbd, const unsigned long long* __restrict__ M,
    float* __restrict__ d_out) {
  int b = blockIdx.x;
  int lane = threadIdx.x;
  for (int k = lane; k < NPOST; k += 64) {
    *(float4*)&d_out[ROIS_OFF + (size_t)(b * NPOST + k) * 4] = make_float4(0, 0, 0, 0);
    d_out[IDX_OFF + b * NPOST + k] = (float)b;
  }
  __syncthreads();

  unsigned long long R = ~0ull;
  if (lane < WORDS) R = 0ull;
  for (int w = 0; w < WORDS; ++w) {
    int j = w * 64 + lane;
    bool inval = true;
    if (j < NPRE) {
      const double* bp = &sbd[((size_t)b * NPRE + j) * 4];
      double h = bp[2] - bp[0], wd = bp[3] - bp[1];
      inval = !(h >= 16.0 && wd >= 16.0);
    }
    unsigned long long bal = __ballot(inval ? 1 : 0);
    if (lane == w) R |= bal;
  }

  int kept = 0;
  while (kept < NPOST) {
    unsigned long long hz = __ballot(((~R) != 0ull) ? 1 : 0);
    if (hz == 0ull) break;
    int w0 = __ffsll(hz) - 1;
    unsigned long long word = __shfl(R, w0);
    int bit = __ffsll(~word) - 1;
    int i = w0 * 64 + bit;
    if (lane < 4)
      d_out[ROIS_OFF + (size_t)(b * NPOST + kept) * 4 + lane] =
          (float)sbd[((size_t)b * NPRE + i) * 4 + lane];
    kept++;
    if (kept >= NPOST) break;
    unsigned long long row = (lane < WORDS)
        ? M[((size_t)b * ROWPAD + i) * WSTRIDE + lane] : 0ull;
    R |= row;
    if (lane == w0) R |= (1ull << bit);
  }
}

// ---------------- launch ----------------
extern "C" void kernel_launch(void* const* d_in, const int* in_sizes, int n_in,
                              void* d_out, int out_size, void* d_ws, size_t ws_size,
                              hipStream_t stream) {
  const float* in     = (const float*)d_in[0];
  const float* conv_w = (const float*)d_in[1];
  const float* conv_b = (const float*)d_in[2];
  const float* bf_w   = (const float*)d_in[3];
  const float* bf_b   = (const float*)d_in[4];
  const float* loc_w  = (const float*)d_in[5];
  const float* loc_b  = (const float*)d_in[6];
  const int*   imh    = (const int*)d_in[7];
  const int*   imw    = (const int*)d_in[8];
  float* out = (float*)d_out;

  char* ws = (char*)d_ws;
  float*  Wt    = (float*)(ws + WS_WT);
  double* rawd  = (double*)(ws + WS_WT);     // aliases Wt (dead after conv3x3)
  float*  W1t   = (float*)(ws + WS_W1T);
  float*  feat  = (float*)(ws + WS_FEAT);
  double* score = (double*)(ws + WS_SCORE);
  double* boxd  = (double*)(ws + WS_BOXD);
  double* sbd   = (double*)(ws + WS_SBD);
  unsigned long long* M = (unsigned long long*)(ws + WS_M);

  hipLaunchKernelGGL(prep_kernel, dim3((4608 * 512 + 512 * 64 + 255) / 256), dim3(256),
                     0, stream, conv_w, loc_w, bf_w, Wt, W1t);
  hipLaunchKernelGGL(conv3x3_kernel, dim3(79, 8), dim3(256), 0, stream,
                     in, Wt, conv_b, feat);
  hipLaunchKernelGGL(conv1x1_kernel, dim3(79), dim3(256), 0, stream,
                     feat, W1t, loc_b, bf_b, rawd);
  hipLaunchKernelGGL(epilogue_kernel, dim3((BIMG * NLOC + 255) / 256), dim3(256), 0, stream,
                     rawd, out, boxd, score, imh, imw);
  hipLaunchKernelGGL(select_kernel, dim3(88, 4), dim3(256), 0, stream,
                     score, boxd, sbd);
  hipLaunchKernelGGL(nmsmask_kernel, dim3(47, 47, 4), dim3(64), 0, stream, sbd, M);
  hipLaunchKernelGGL(nms_scan_kernel, dim3(4), dim3(64), 0, stream, sbd, M, out);
}

// Round 3
// 2635.983 us; speedup vs baseline: 1.0367x; 1.0367x over previous
//
#include <hip/hip_runtime.h>
#include <hip/hip_bf16.h>
#include <math.h>

// ---------------- problem constants ----------------
#define BIMG   4
#define CIN    512
#define MID    512
#define HF     50
#define WF     50
#define PIX    2500          // HF*WF
#define MTOT   10000         // BIMG*PIX
#define ANC    9
#define NLOC   22500         // PIX*ANC
#define NPRE   3000
#define NPOST  300
#define WORDS  47            // ceil(3000/64)
#define ROWPAD 3008
#define WSTRIDE 48           // padded words per NMS row

// d_out layout (floats): rois, rois_idx, anchors, loc, bf_pred
#define ROIS_OFF 0
#define IDX_OFF  4800
#define ANC_OFF  6000
#define LOC_OFF  96000
#define BF_OFF   456000

// ws layout (byte offsets). raw (f64) aliases Wt (dead after conv3x3).
#define WS_WT     0UL                      // 4608*512 f32   = 9,437,184 B (raw f64 5,120,000 aliased)
#define WS_W1T    9437184UL                // 512*64 f32     =   131,072 B
#define WS_FEAT   9568256UL                // 10000*512 f32  = 20,480,000 B
#define WS_SCORE  30048256UL               // 90000 f64      =    720,000 B
#define WS_BOXD   30768256UL               // 90000*4 f64    =  2,880,000 B
#define WS_SBD    33648256UL               // 4*3000*4 f64   =    384,000 B
#define WS_M      34032256UL               // 4*3008*48 u64  =  4,620,288 B
// total = 38,652,544 B (~36.9 MiB)

// ---------------- kernel 0: weight prep ----------------
__global__ __launch_bounds__(256) void prep_kernel(
    const float* __restrict__ conv_w, const float* __restrict__ loc_w,
    const float* __restrict__ bf_w, float* __restrict__ Wt, float* __restrict__ W1t) {
  int o = blockIdx.x * 256 + threadIdx.x;
  if (o < 4608 * 512) {
    int co  = o & 511;
    int k   = o >> 9;          // tap*512 + c
    int c   = k & 511;
    int tap = k >> 9;
    Wt[o] = conv_w[(co * 512 + c) * 9 + tap];
  } else {
    int o2 = o - 4608 * 512;
    if (o2 < 512 * 64) {
      int co = o2 & 63;
      int c  = o2 >> 6;
      float v = 0.0f;
      if (co < 36)      v = loc_w[co * 512 + c];
      else if (co < 54) v = bf_w[(co - 36) * 512 + c];
      W1t[o2] = v;
    }
  }
}

// ---------------- kernel 1: 3x3 conv + bias + relu ----------------
// f32 FMA inner MACs (exact products), f64 fold per 16-K block.
// Double-buffered LDS, register-pipelined staging, ONE barrier per kb.
// feat stored NHWC f32: feat[q*512 + co]
__global__ __launch_bounds__(256) void conv3x3_kernel(
    const float* __restrict__ in, const float* __restrict__ Wt,
    const float* __restrict__ bias, float* __restrict__ feat) {
  __shared__ float As[2][16][132];
  __shared__ float Bs[2][16][68];
  int tid = threadIdx.x;
  int q0  = blockIdx.x * 128;
  int co0 = blockIdx.y * 64;
  int tx = tid & 15, ty = tid >> 4;

  int pix = tid & 127;
  int kk0 = tid >> 7;           // 0 or 1
  int q   = q0 + pix;
  bool inimg = q < MTOT;
  int qq = inimg ? q : 0;
  int b  = qq / PIX;
  int r  = qq - b * PIX;
  int y  = r / WF;
  int x  = r - y * WF;
  const float* inb = in + (size_t)b * (CIN * PIX);

  double acc[8][4];
#pragma unroll
  for (int i = 0; i < 8; ++i)
#pragma unroll
    for (int j = 0; j < 4; ++j) acc[i][j] = 0.0;

  // ---- prologue: stage kb=0 into buffer 0 ----
  {
    bool ok0 = inimg && (y >= 1) && (x >= 1);   // tap 0: dy=-1,dx=-1
    int base0 = kk0 * PIX + (y - 1) * WF + (x - 1);
#pragma unroll
    for (int k = 0; k < 8; ++k)
      As[0][kk0 + k * 2][pix] = ok0 ? inb[base0 + k * 2 * PIX] : 0.0f;
    const float* wb = Wt + co0;
#pragma unroll
    for (int k = 0; k < 4; ++k) {
      int L = tid + k * 256;
      Bs[0][L >> 6][L & 63] = wb[(L >> 6) * 512 + (L & 63)];
    }
  }
  __syncthreads();

  for (int kb = 0; kb < 288; ++kb) {
    int cur = kb & 1;
    // ---- issue next tile's global loads into registers (latency hidden by compute) ----
    float av[8];
    float bv[4];
    bool has_next = (kb + 1 < 288);
    if (has_next) {
      int kb1 = kb + 1;
      int tap = kb1 >> 5;
      int c0  = (kb1 & 31) << 4;
      int t3  = tap / 3;
      int dy  = t3 - 1;
      int dx  = tap - t3 * 3 - 1;
      int iy  = y + dy, ix = x + dx;
      bool ok = inimg && ((unsigned)iy < (unsigned)HF) && ((unsigned)ix < (unsigned)WF);
      int base = (c0 + kk0) * PIX + iy * WF + ix;
#pragma unroll
      for (int k = 0; k < 8; ++k) av[k] = ok ? inb[base + k * 2 * PIX] : 0.0f;
      const float* wb = Wt + (size_t)(kb1 * 16) * 512 + co0;
#pragma unroll
      for (int k = 0; k < 4; ++k) {
        int L = tid + k * 256;
        bv[k] = wb[(L >> 6) * 512 + (L & 63)];
      }
    }

    // ---- compute 16-K block in f32 (exact FMA products) ----
    float accf[8][4];
#pragma unroll
    for (int i = 0; i < 8; ++i)
#pragma unroll
      for (int j = 0; j < 4; ++j) accf[i][j] = 0.0f;

#pragma unroll
    for (int kk = 0; kk < 16; ++kk) {
      float a0[8], b0[4];
      *(float4*)&a0[0] = *(const float4*)&As[cur][kk][ty * 8];
      *(float4*)&a0[4] = *(const float4*)&As[cur][kk][ty * 8 + 4];
      *(float4*)&b0[0] = *(const float4*)&Bs[cur][kk][tx * 4];
#pragma unroll
      for (int i = 0; i < 8; ++i)
#pragma unroll
        for (int j = 0; j < 4; ++j) accf[i][j] = fmaf(a0[i], b0[j], accf[i][j]);
    }
    // ---- fold block into f64 accumulators ----
#pragma unroll
    for (int i = 0; i < 8; ++i)
#pragma unroll
      for (int j = 0; j < 4; ++j) acc[i][j] += (double)accf[i][j];

    // ---- write next tile to the other LDS buffer ----
    if (has_next) {
      int nxt = cur ^ 1;
#pragma unroll
      for (int k = 0; k < 8; ++k) As[nxt][kk0 + k * 2][pix] = av[k];
#pragma unroll
      for (int k = 0; k < 4; ++k) {
        int L = tid + k * 256;
        Bs[nxt][L >> 6][L & 63] = bv[k];
      }
    }
    __syncthreads();
  }

  float4 bsv = *(const float4*)&bias[co0 + tx * 4];
  double bd4[4] = {(double)bsv.x, (double)bsv.y, (double)bsv.z, (double)bsv.w};
#pragma unroll
  for (int i = 0; i < 8; ++i) {
    int qo = q0 + ty * 8 + i;
    if (qo < MTOT) {
      float4 o;
      o.x = (float)fmax(acc[i][0] + bd4[0], 0.0);
      o.y = (float)fmax(acc[i][1] + bd4[1], 0.0);
      o.z = (float)fmax(acc[i][2] + bd4[2], 0.0);
      o.w = (float)fmax(acc[i][3] + bd4[3], 0.0);
      *(float4*)&feat[(size_t)qo * 512 + co0 + tx * 4] = o;
    }
  }
}

// ---------------- kernel 2: fused 1x1 heads, f64 accumulate, f64 raw output ----------------
__global__ __launch_bounds__(256) void conv1x1_kernel(
    const float* __restrict__ feat, const float* __restrict__ W1t,
    const float* __restrict__ locb, const float* __restrict__ bfb,
    double* __restrict__ rawd) {
  __shared__ float As[16][132];
  __shared__ float Bs[16][68];
  int tid = threadIdx.x;
  int q0  = blockIdx.x * 128;
  int tx = tid & 15, ty = tid >> 4;
  int pixL = tid >> 1;
  int ch   = (tid & 1) * 8;
  int qL   = q0 + pixL;
  bool okL = qL < MTOT;

  double acc[8][4];
#pragma unroll
  for (int i = 0; i < 8; ++i)
#pragma unroll
    for (int j = 0; j < 4; ++j) acc[i][j] = 0.0;

  for (int kb = 0; kb < 32; ++kb) {
    int c0 = kb * 16;
    float4 f0 = make_float4(0, 0, 0, 0), f1 = make_float4(0, 0, 0, 0);
    if (okL) {
      const float* fp = &feat[(size_t)qL * 512 + c0 + ch];
      f0 = *(const float4*)fp;
      f1 = *(const float4*)(fp + 4);
    }
    As[ch + 0][pixL] = f0.x; As[ch + 1][pixL] = f0.y;
    As[ch + 2][pixL] = f0.z; As[ch + 3][pixL] = f0.w;
    As[ch + 4][pixL] = f1.x; As[ch + 5][pixL] = f1.y;
    As[ch + 6][pixL] = f1.z; As[ch + 7][pixL] = f1.w;
#pragma unroll
    for (int k = 0; k < 4; ++k) {
      int L = tid + k * 256;
      int kk = L >> 6, co = L & 63;
      Bs[kk][co] = W1t[(c0 + kk) * 64 + co];
    }
    __syncthreads();
#pragma unroll
    for (int kk = 0; kk < 16; ++kk) {
      float a0[8], b0[4];
      *(float4*)&a0[0] = *(const float4*)&As[kk][ty * 8];
      *(float4*)&a0[4] = *(const float4*)&As[kk][ty * 8 + 4];
      *(float4*)&b0[0] = *(const float4*)&Bs[kk][tx * 4];
      double ad[8], bd[4];
#pragma unroll
      for (int i = 0; i < 8; ++i) ad[i] = (double)a0[i];
#pragma unroll
      for (int j = 0; j < 4; ++j) bd[j] = (double)b0[j];
#pragma unroll
      for (int i = 0; i < 8; ++i)
#pragma unroll
        for (int j = 0; j < 4; ++j) acc[i][j] = fma(ad[i], bd[j], acc[i][j]);
    }
    __syncthreads();
  }
  double bs[4];
#pragma unroll
  for (int j = 0; j < 4; ++j) {
    int co = tx * 4 + j;
    bs[j] = (co < 36) ? (double)locb[co] : ((co < 54) ? (double)bfb[co - 36] : 0.0);
  }
#pragma unroll
  for (int i = 0; i < 8; ++i) {
    int qo = q0 + ty * 8 + i;
    if (qo < MTOT) {
      double* rp = &rawd[(size_t)qo * 64 + tx * 4];
      rp[0] = acc[i][0] + bs[0];
      rp[1] = acc[i][1] + bs[1];
      rp[2] = acc[i][2] + bs[2];
      rp[3] = acc[i][3] + bs[3];
    }
  }
}

// ---------------- kernel 3: epilogue — f64 softmax/decode/clip, score=d (f64) ----------------
__global__ __launch_bounds__(256) void epilogue_kernel(
    const double* __restrict__ rawd, float* __restrict__ d_out,
    double* __restrict__ boxd, double* __restrict__ score,
    const int* __restrict__ imh, const int* __restrict__ imw) {
  int idx = blockIdx.x * 256 + threadIdx.x;
  if (idx >= BIMG * NLOC) return;
  int b = idx / NLOC;
  int i = idx - b * NLOC;
  int p = i / ANC;
  int a = i - p * ANC;
  int y = p / WF;
  int x = p - y * WF;
  int q = b * PIX + p;

  // loc (raw regression output)
  double l0d = rawd[(size_t)q * 64 + a * 4 + 0];
  double l1d = rawd[(size_t)q * 64 + a * 4 + 1];
  double l2d = rawd[(size_t)q * 64 + a * 4 + 2];
  double l3d = rawd[(size_t)q * 64 + a * 4 + 3];
  float4 lo = make_float4((float)l0d, (float)l1d, (float)l2d, (float)l3d);
  *(float4*)&d_out[LOC_OFF + (size_t)idx * 4] = lo;

  // softmax over 2 logits (f64)
  double g0 = rawd[(size_t)q * 64 + 36 + a * 2];
  double g1 = rawd[(size_t)q * 64 + 37 + a * 2];
  double m  = fmax(g0, g1);
  double e0 = exp(g0 - m), e1 = exp(g1 - m);
  double s  = e0 + e1;
  double p0 = e0 / s, p1 = e1 / s;
  *(float2*)&d_out[BF_OFF + (size_t)idx * 2] = make_float2((float)p0, (float)p1);

  // anchor (f64)
  int ridx = a / 3, sidx = a - ridx * 3;
  double ratio = (ridx == 0) ? 0.5 : ((ridx == 1) ? 1.0 : 2.0);
  double scale = (sidx == 0) ? 8.0 : ((sidx == 1) ? 16.0 : 32.0);
  double hs = 16.0 * scale * sqrt(ratio);
  double ws = 16.0 * scale * sqrt(1.0 / ratio);
  double sy = (double)(y * 16), sx = (double)(x * 16);
  double a0 = sy + (8.0 - hs * 0.5);
  double a1 = sx + (8.0 - ws * 0.5);
  double a2 = sy + (8.0 + hs * 0.5);
  double a3 = sx + (8.0 + ws * 0.5);
  if (b == 0) {
    *(float4*)&d_out[ANC_OFF + (size_t)i * 4] =
        make_float4((float)a0, (float)a1, (float)a2, (float)a3);
  }

  // decode + clip (f64)
  double ah = a2 - a0, aw = a3 - a1;
  double acy = a0 + 0.5 * ah, acx = a1 + 0.5 * aw;
  double cy = l0d * ah + acy;
  double cx = l1d * aw + acx;
  double hh = exp(l2d) * ah;
  double ww = exp(l3d) * aw;
  double ihf = (double)imh[0], iwf = (double)imw[0];
  double b0 = fmin(fmax(cy - 0.5 * hh, 0.0), ihf);
  double b1 = fmin(fmax(cx - 0.5 * ww, 0.0), iwf);
  double b2 = fmin(fmax(cy + 0.5 * hh, 0.0), ihf);
  double b3 = fmin(fmax(cx + 0.5 * ww, 0.0), iwf);
  double* bp = &boxd[(size_t)idx * 4];
  bp[0] = b0; bp[1] = b1; bp[2] = b2; bp[3] = b3;

  bool valid = (b2 - b0 >= 16.0) && (b3 - b1 >= 16.0);
  // ordering key: p1 is a strictly monotone f64 function of d = g1-g0;
  // sorting by d (desc, idx-asc ties) == np argsort(-p1) stable.
  score[idx] = valid ? (g1 - g0) : -INFINITY;
}

// ---------------- kernel 4: exact top-3000 by rank counting (f64 scores) ----------------
__global__ __launch_bounds__(256) void select_kernel(
    const double* __restrict__ score, const double* __restrict__ boxd,
    double* __restrict__ sbd) {
  __shared__ double kt[256];
  int b = blockIdx.y;
  int i = blockIdx.x * 256 + threadIdx.x;
  bool act = i < NLOC;
  double myd = act ? score[(size_t)b * NLOC + i] : -INFINITY;
  int cnt = 0;
  for (int t = 0; t < 88; ++t) {
    int j0 = t * 256;
    int j = j0 + threadIdx.x;
    kt[threadIdx.x] = (j < NLOC) ? score[(size_t)b * NLOC + j] : -INFINITY;
    __syncthreads();
#pragma unroll 4
    for (int jj = 0; jj < 256; ++jj) {
      double dj = kt[jj];
      int jidx = j0 + jj;
      cnt += ((dj > myd) || (dj == myd && jidx < i)) ? 1 : 0;
    }
    __syncthreads();
  }
  if (act && cnt < NPRE) {
    const double* bx = &boxd[((size_t)b * NLOC + i) * 4];
    double* dp = &sbd[((size_t)b * NPRE + cnt) * 4];
    dp[0] = bx[0]; dp[1] = bx[1]; dp[2] = bx[2]; dp[3] = bx[3];
  }
}

// ---------------- kernel 5: NMS suppression bitmask matrix (f64 IoU) ----------------
__global__ __launch_bounds__(64) void nmsmask_kernel(
    const double* __restrict__ sbd, unsigned long long* __restrict__ M) {
  __shared__ double cb[64][4];
  int b = blockIdx.z;
  int jw = blockIdx.y;                 // column word 0..46
  int i  = blockIdx.x * 64 + threadIdx.x;
  int j  = jw * 64 + threadIdx.x;
  double j0 = 0, j1 = 0, j2 = 0, j3 = 0;
  if (j < NPRE) {
    const double* bp = &sbd[((size_t)b * NPRE + j) * 4];
    j0 = bp[0]; j1 = bp[1]; j2 = bp[2]; j3 = bp[3];
  }
  cb[threadIdx.x][0] = j0; cb[threadIdx.x][1] = j1;
  cb[threadIdx.x][2] = j2; cb[threadIdx.x][3] = j3;
  __syncthreads();
  if (i >= NPRE) return;
  const double* bp = &sbd[((size_t)b * NPRE + i) * 4];
  double i0 = bp[0], i1 = bp[1], i2 = bp[2], i3 = bp[3];
  double ai = (i2 - i0) * (i3 - i1);
  unsigned long long mask = 0ull;
#pragma unroll 4
  for (int t = 0; t < 64; ++t) {
    double aj = (cb[t][2] - cb[t][0]) * (cb[t][3] - cb[t][1]);
    double h = fmax(fmin(i2, cb[t][2]) - fmax(i0, cb[t][0]), 0.0);
    double w = fmax(fmin(i3, cb[t][3]) - fmax(i1, cb[t][1]), 0.0);
    double inter = h * w;
    double iou = inter / (ai + aj - inter + 1e-9);
    mask |= ((iou > 0.7) ? 1ull : 0ull) << t;
  }
  M[((size_t)b * ROWPAD + i) * WSTRIDE + jw] = mask;
}

// ---------------- kernel 6: sequential NMS scan (1 wave / image) ----------------
__global__ __launch_bounds__(64) void nms_scan_kernel(
    const double* __restrict__ sbd, const unsigned long long* __restrict__ M,
    float* __restrict__ d_out) {
  int b = blockIdx.x;
  int lane = threadIdx.x;
  for (int k = lane; k < NPOST; k += 64) {
    *(float4*)&d_out[ROIS_OFF + (size_t)(b * NPOST + k) * 4] = make_float4(0, 0, 0, 0);
    d_out[IDX_OFF + b * NPOST + k] = (float)b;
  }
  __syncthreads();

  unsigned long long R = ~0ull;
  if (lane < WORDS) R = 0ull;
  for (int w = 0; w < WORDS; ++w) {
    int j = w * 64 + lane;
    bool inval = true;
    if (j < NPRE) {
      const double* bp = &sbd[((size_t)b * NPRE + j) * 4];
      double h = bp[2] - bp[0], wd = bp[3] - bp[1];
      inval = !(h >= 16.0 && wd >= 16.0);
    }
    unsigned long long bal = __ballot(inval ? 1 : 0);
    if (lane == w) R |= bal;
  }

  int kept = 0;
  while (kept < NPOST) {
    unsigned long long hz = __ballot(((~R) != 0ull) ? 1 : 0);
    if (hz == 0ull) break;
    int w0 = __ffsll(hz) - 1;
    unsigned long long word = __shfl(R, w0);
    int bit = __ffsll(~word) - 1;
    int i = w0 * 64 + bit;
    if (lane < 4)
      d_out[ROIS_OFF + (size_t)(b * NPOST + kept) * 4 + lane] =
          (float)sbd[((size_t)b * NPRE + i) * 4 + lane];
    kept++;
    if (kept >= NPOST) break;
    unsigned long long row = (lane < WORDS)
        ? M[((size_t)b * ROWPAD + i) * WSTRIDE + lane] : 0ull;
    R |= row;
    if (lane == w0) R |= (1ull << bit);
  }
}

// ---------------- launch ----------------
extern "C" void kernel_launch(void* const* d_in, const int* in_sizes, int n_in,
                              void* d_out, int out_size, void* d_ws, size_t ws_size,
                              hipStream_t stream) {
  const float* in     = (const float*)d_in[0];
  const float* conv_w = (const float*)d_in[1];
  const float* conv_b = (const float*)d_in[2];
  const float* bf_w   = (const float*)d_in[3];
  const float* bf_b   = (const float*)d_in[4];
  const float* loc_w  = (const float*)d_in[5];
  const float* loc_b  = (const float*)d_in[6];
  const int*   imh    = (const int*)d_in[7];
  const int*   imw    = (const int*)d_in[8];
  float* out = (float*)d_out;

  char* ws = (char*)d_ws;
  float*  Wt    = (float*)(ws + WS_WT);
  double* rawd  = (double*)(ws + WS_WT);     // aliases Wt (dead after conv3x3)
  float*  W1t   = (float*)(ws + WS_W1T);
  float*  feat  = (float*)(ws + WS_FEAT);
  double* score = (double*)(ws + WS_SCORE);
  double* boxd  = (double*)(ws + WS_BOXD);
  double* sbd   = (double*)(ws + WS_SBD);
  unsigned long long* M = (unsigned long long*)(ws + WS_M);

  hipLaunchKernelGGL(prep_kernel, dim3((4608 * 512 + 512 * 64 + 255) / 256), dim3(256),
                     0, stream, conv_w, loc_w, bf_w, Wt, W1t);
  hipLaunchKernelGGL(conv3x3_kernel, dim3(79, 8), dim3(256), 0, stream,
                     in, Wt, conv_b, feat);
  hipLaunchKernelGGL(conv1x1_kernel, dim3(79), dim3(256), 0, stream,
                     feat, W1t, loc_b, bf_b, rawd);
  hipLaunchKernelGGL(epilogue_kernel, dim3((BIMG * NLOC + 255) / 256), dim3(256), 0, stream,
                     rawd, out, boxd, score, imh, imw);
  hipLaunchKernelGGL(select_kernel, dim3(88, 4), dim3(256), 0, stream,
                     score, boxd, sbd);
  hipLaunchKernelGGL(nmsmask_kernel, dim3(47, 47, 4), dim3(64), 0, stream, sbd, M);
  hipLaunchKernelGGL(nms_scan_kernel, dim3(4), dim3(64), 0, stream, sbd, M, out);
}

// Round 4
// 2185.215 us; speedup vs baseline: 1.2505x; 1.2063x over previous
//
#include <hip/hip_runtime.h>
#include <hip/hip_bf16.h>
#include <math.h>

// ---------------- problem constants ----------------
#define BIMG   4
#define CIN    512
#define MID    512
#define HF     50
#define WF     50
#define PIX    2500          // HF*WF
#define MTOT   10000         // BIMG*PIX
#define ANC    9
#define NLOC   22500         // PIX*ANC
#define NPRE   3000
#define NPOST  300
#define WORDS  47            // ceil(3000/64)
#define ROWPAD 3008
#define WSTRIDE 48           // padded words per NMS row

// d_out layout (floats): rois, rois_idx, anchors, loc, bf_pred
#define ROIS_OFF 0
#define IDX_OFF  4800
#define ANC_OFF  6000
#define LOC_OFF  96000
#define BF_OFF   456000

// ws layout (byte offsets). raw (f64) aliases Wt (dead after conv3x3).
#define WS_WT     0UL                      // 4608*512 f32   = 9,437,184 B (raw f64 5,120,000 aliased)
#define WS_W1T    9437184UL                // 512*64 f32     =   131,072 B
#define WS_FEAT   9568256UL                // 10000*512 f32  = 20,480,000 B
#define WS_SCORE  30048256UL               // 90000 u64 keys =    720,000 B
#define WS_BOXD   30768256UL               // 90000*4 f64    =  2,880,000 B
#define WS_SBD    33648256UL               // 4*3000*4 f64   =    384,000 B
#define WS_M      34032256UL               // 4*3008*48 u64  =  4,620,288 B
// total = 38,652,544 B (~36.9 MiB)

// ---------------- kernel 0: weight prep ----------------
// Wt[(tap*512 + c)*512 + co] = conv_w[co][c][tap]
__global__ __launch_bounds__(256) void prep_kernel(
    const float* __restrict__ conv_w, const float* __restrict__ loc_w,
    const float* __restrict__ bf_w, float* __restrict__ Wt, float* __restrict__ W1t) {
  int o = blockIdx.x * 256 + threadIdx.x;
  if (o < 4608 * 512) {
    int co  = o & 511;
    int k   = o >> 9;          // tap*512 + c
    int c   = k & 511;
    int tap = k >> 9;
    Wt[o] = conv_w[(co * 512 + c) * 9 + tap];
  } else {
    int o2 = o - 4608 * 512;
    if (o2 < 512 * 64) {
      int co = o2 & 63;
      int c  = o2 >> 6;
      float v = 0.0f;
      if (co < 36)      v = loc_w[co * 512 + c];
      else if (co < 54) v = bf_w[(co - 36) * 512 + c];
      W1t[o2] = v;
    }
  }
}

// ---------------- kernel 1: 3x3 conv + bias + relu ----------------
// Wave-uniform-B structure: each wave owns 8 output cols; B comes from
// global via scalar (s_load) path, A streams through LDS (8 B/lane/kk).
// f32 FMA inner, f64 fold every 2 K-blocks. M=128/block, 32 cols/block.
__device__ __forceinline__ void stage_load(
    int kb, int sg, bool in0, bool in1,
    int y0, int x0, int y1, int x1,
    const float* __restrict__ ib0, const float* __restrict__ ib1, float av[8]) {
  int tap = kb >> 5;
  int c0  = (kb & 31) << 4;
  int t3  = tap / 3;
  int dy  = t3 - 1;
  int dx  = tap - t3 * 3 - 1;
  int iy0 = y0 + dy, ix0 = x0 + dx;
  int iy1 = y1 + dy, ix1 = x1 + dx;
  bool ok0 = in0 && ((unsigned)iy0 < (unsigned)HF) && ((unsigned)ix0 < (unsigned)WF);
  bool ok1 = in1 && ((unsigned)iy1 < (unsigned)HF) && ((unsigned)ix1 < (unsigned)WF);
  int base = (c0 + sg * 4) * PIX;
  int o0 = iy0 * WF + ix0;
  int o1 = iy1 * WF + ix1;
#pragma unroll
  for (int j = 0; j < 4; ++j) {
    av[2 * j]     = ok0 ? ib0[base + j * PIX + o0] : 0.0f;
    av[2 * j + 1] = ok1 ? ib1[base + j * PIX + o1] : 0.0f;
  }
}

__global__ __launch_bounds__(256) void conv3x3_kernel(
    const float* __restrict__ in, const float* __restrict__ Wt,
    const float* __restrict__ bias, float* __restrict__ feat) {
  __shared__ float As[2][16][128];
  const int tid = threadIdx.x;
  const int q0 = blockIdx.x * 128;
  const int colbase = blockIdx.y * 32;
  const int lane = tid & 63;
  const int wv = tid >> 6;
  // wave-uniform column base -> scalar B loads
  const int col0 = __builtin_amdgcn_readfirstlane(colbase + wv * 8);

  // staging geometry: thread handles pixel pair (2*sp, 2*sp+1), kk-quad sg
  const int sg = tid >> 6;
  const int sp = tid & 63;
  int qs0 = q0 + 2 * sp, qs1 = qs0 + 1;
  bool in0 = qs0 < MTOT, in1 = qs1 < MTOT;
  int t0 = in0 ? qs0 : 0, t1 = in1 ? qs1 : 0;
  int b0i = t0 / PIX, r0 = t0 - b0i * PIX, y0 = r0 / WF, x0 = r0 - y0 * WF;
  int b1i = t1 / PIX, r1 = t1 - b1i * PIX, y1 = r1 / WF, x1 = r1 - y1 * WF;
  const float* ib0 = in + (size_t)b0i * (CIN * PIX);
  const float* ib1 = in + (size_t)b1i * (CIN * PIX);

  double acc[2][8];
  float accf[2][8];
#pragma unroll
  for (int p = 0; p < 2; ++p)
#pragma unroll
    for (int c = 0; c < 8; ++c) { acc[p][c] = 0.0; accf[p][c] = 0.0f; }

  // prologue: stage kb=0 into buffer 0
  {
    float av[8];
    stage_load(0, sg, in0, in1, y0, x0, y1, x1, ib0, ib1, av);
#pragma unroll
    for (int j = 0; j < 4; ++j)
      *(float2*)&As[0][sg * 4 + j][2 * sp] = make_float2(av[2 * j], av[2 * j + 1]);
  }
  __syncthreads();

  for (int kb = 0; kb < 288; ++kb) {
    int cur = kb & 1;
    float av[8];
    bool has_next = (kb + 1 < 288);
    if (has_next)
      stage_load(kb + 1, sg, in0, in1, y0, x0, y1, x1, ib0, ib1, av);

    const float* __restrict__ Bw = Wt + (size_t)(kb * 16) * 512 + col0;
#pragma unroll
    for (int kk = 0; kk < 16; ++kk) {
      float2 a = *(const float2*)&As[cur][kk][2 * lane];
      const float* __restrict__ br = Bw + (size_t)kk * 512;
#pragma unroll
      for (int c = 0; c < 8; ++c) {
        float bv = br[c];          // wave-uniform -> SGPR
        accf[0][c] = fmaf(a.x, bv, accf[0][c]);
        accf[1][c] = fmaf(a.y, bv, accf[1][c]);
      }
    }
    if (kb & 1) {                  // fold every 2 kb (288 even -> last fold at kb=287)
#pragma unroll
      for (int p = 0; p < 2; ++p)
#pragma unroll
        for (int c = 0; c < 8; ++c) {
          acc[p][c] += (double)accf[p][c];
          accf[p][c] = 0.0f;
        }
    }
    if (has_next) {
      int nxt = cur ^ 1;
#pragma unroll
      for (int j = 0; j < 4; ++j)
        *(float2*)&As[nxt][sg * 4 + j][2 * sp] = make_float2(av[2 * j], av[2 * j + 1]);
    }
    __syncthreads();
  }

  double bd[8];
#pragma unroll
  for (int c = 0; c < 8; ++c) bd[c] = (double)bias[col0 + c];
#pragma unroll
  for (int p = 0; p < 2; ++p) {
    int q = q0 + 2 * lane + p;
    if (q < MTOT) {
      float o[8];
#pragma unroll
      for (int c = 0; c < 8; ++c)
        o[c] = (float)fmax(acc[p][c] + bd[c], 0.0);
      *(float4*)&feat[(size_t)q * 512 + col0]     = make_float4(o[0], o[1], o[2], o[3]);
      *(float4*)&feat[(size_t)q * 512 + col0 + 4] = make_float4(o[4], o[5], o[6], o[7]);
    }
  }
}

// ---------------- kernel 2: fused 1x1 heads, f64 accumulate, f64 raw output ----------------
__global__ __launch_bounds__(256) void conv1x1_kernel(
    const float* __restrict__ feat, const float* __restrict__ W1t,
    const float* __restrict__ locb, const float* __restrict__ bfb,
    double* __restrict__ rawd) {
  __shared__ float As[16][132];
  __shared__ float Bs[16][68];
  int tid = threadIdx.x;
  int q0  = blockIdx.x * 128;
  int tx = tid & 15, ty = tid >> 4;
  int pixL = tid >> 1;
  int ch   = (tid & 1) * 8;
  int qL   = q0 + pixL;
  bool okL = qL < MTOT;

  double acc[8][4];
#pragma unroll
  for (int i = 0; i < 8; ++i)
#pragma unroll
    for (int j = 0; j < 4; ++j) acc[i][j] = 0.0;

  for (int kb = 0; kb < 32; ++kb) {
    int c0 = kb * 16;
    float4 f0 = make_float4(0, 0, 0, 0), f1 = make_float4(0, 0, 0, 0);
    if (okL) {
      const float* fp = &feat[(size_t)qL * 512 + c0 + ch];
      f0 = *(const float4*)fp;
      f1 = *(const float4*)(fp + 4);
    }
    As[ch + 0][pixL] = f0.x; As[ch + 1][pixL] = f0.y;
    As[ch + 2][pixL] = f0.z; As[ch + 3][pixL] = f0.w;
    As[ch + 4][pixL] = f1.x; As[ch + 5][pixL] = f1.y;
    As[ch + 6][pixL] = f1.z; As[ch + 7][pixL] = f1.w;
#pragma unroll
    for (int k = 0; k < 4; ++k) {
      int L = tid + k * 256;
      int kk = L >> 6, co = L & 63;
      Bs[kk][co] = W1t[(c0 + kk) * 64 + co];
    }
    __syncthreads();
#pragma unroll
    for (int kk = 0; kk < 16; ++kk) {
      float a0[8], b0[4];
      *(float4*)&a0[0] = *(const float4*)&As[kk][ty * 8];
      *(float4*)&a0[4] = *(const float4*)&As[kk][ty * 8 + 4];
      *(float4*)&b0[0] = *(const float4*)&Bs[kk][tx * 4];
      double ad[8], bd[4];
#pragma unroll
      for (int i = 0; i < 8; ++i) ad[i] = (double)a0[i];
#pragma unroll
      for (int j = 0; j < 4; ++j) bd[j] = (double)b0[j];
#pragma unroll
      for (int i = 0; i < 8; ++i)
#pragma unroll
        for (int j = 0; j < 4; ++j) acc[i][j] = fma(ad[i], bd[j], acc[i][j]);
    }
    __syncthreads();
  }
  double bs[4];
#pragma unroll
  for (int j = 0; j < 4; ++j) {
    int co = tx * 4 + j;
    bs[j] = (co < 36) ? (double)locb[co] : ((co < 54) ? (double)bfb[co - 36] : 0.0);
  }
#pragma unroll
  for (int i = 0; i < 8; ++i) {
    int qo = q0 + ty * 8 + i;
    if (qo < MTOT) {
      double* rp = &rawd[(size_t)qo * 64 + tx * 4];
      rp[0] = acc[i][0] + bs[0];
      rp[1] = acc[i][1] + bs[1];
      rp[2] = acc[i][2] + bs[2];
      rp[3] = acc[i][3] + bs[3];
    }
  }
}

// ---------------- kernel 3: epilogue — f64 softmax/decode/clip, u64 sort keys ----------------
__global__ __launch_bounds__(256) void epilogue_kernel(
    const double* __restrict__ rawd, float* __restrict__ d_out,
    double* __restrict__ boxd, unsigned long long* __restrict__ ukey,
    const int* __restrict__ imh, const int* __restrict__ imw) {
  int idx = blockIdx.x * 256 + threadIdx.x;
  if (idx >= BIMG * NLOC) return;
  int b = idx / NLOC;
  int i = idx - b * NLOC;
  int p = i / ANC;
  int a = i - p * ANC;
  int y = p / WF;
  int x = p - y * WF;
  int q = b * PIX + p;

  double l0d = rawd[(size_t)q * 64 + a * 4 + 0];
  double l1d = rawd[(size_t)q * 64 + a * 4 + 1];
  double l2d = rawd[(size_t)q * 64 + a * 4 + 2];
  double l3d = rawd[(size_t)q * 64 + a * 4 + 3];
  float4 lo = make_float4((float)l0d, (float)l1d, (float)l2d, (float)l3d);
  *(float4*)&d_out[LOC_OFF + (size_t)idx * 4] = lo;

  double g0 = rawd[(size_t)q * 64 + 36 + a * 2];
  double g1 = rawd[(size_t)q * 64 + 37 + a * 2];
  double m  = fmax(g0, g1);
  double e0 = exp(g0 - m), e1 = exp(g1 - m);
  double s  = e0 + e1;
  double p0 = e0 / s, p1 = e1 / s;
  *(float2*)&d_out[BF_OFF + (size_t)idx * 2] = make_float2((float)p0, (float)p1);

  int ridx = a / 3, sidx = a - ridx * 3;
  double ratio = (ridx == 0) ? 0.5 : ((ridx == 1) ? 1.0 : 2.0);
  double scale = (sidx == 0) ? 8.0 : ((sidx == 1) ? 16.0 : 32.0);
  double hs = 16.0 * scale * sqrt(ratio);
  double ws = 16.0 * scale * sqrt(1.0 / ratio);
  double sy = (double)(y * 16), sx = (double)(x * 16);
  double a0 = sy + (8.0 - hs * 0.5);
  double a1 = sx + (8.0 - ws * 0.5);
  double a2 = sy + (8.0 + hs * 0.5);
  double a3 = sx + (8.0 + ws * 0.5);
  if (b == 0) {
    *(float4*)&d_out[ANC_OFF + (size_t)i * 4] =
        make_float4((float)a0, (float)a1, (float)a2, (float)a3);
  }

  double ah = a2 - a0, aw = a3 - a1;
  double acy = a0 + 0.5 * ah, acx = a1 + 0.5 * aw;
  double cy = l0d * ah + acy;
  double cx = l1d * aw + acx;
  double hh = exp(l2d) * ah;
  double ww = exp(l3d) * aw;
  double ihf = (double)imh[0], iwf = (double)imw[0];
  double b0 = fmin(fmax(cy - 0.5 * hh, 0.0), ihf);
  double b1 = fmin(fmax(cx - 0.5 * ww, 0.0), iwf);
  double b2 = fmin(fmax(cy + 0.5 * hh, 0.0), ihf);
  double b3 = fmin(fmax(cx + 0.5 * ww, 0.0), iwf);
  double* bp = &boxd[(size_t)idx * 4];
  bp[0] = b0; bp[1] = b1; bp[2] = b2; bp[3] = b3;

  bool valid = (b2 - b0 >= 16.0) && (b3 - b1 >= 16.0);
  // d = g1-g0 is strictly monotone in p1; map f64 -> order-preserving u64,
  // invert for descending. Bit-exact: ordering identical to f64 compare.
  double d = valid ? (g1 - g0) : -INFINITY;
  long long bits = __double_as_longlong(d);
  unsigned long long u = (bits < 0)
      ? ~(unsigned long long)bits
      : ((unsigned long long)bits | 0x8000000000000000ull);
  ukey[idx] = ~u;   // smaller key = better rank
}

// ---------------- kernel 4: exact top-3000 by rank counting (u64 keys) ----------------
__global__ __launch_bounds__(256) void select_kernel(
    const unsigned long long* __restrict__ ukey, const double* __restrict__ boxd,
    double* __restrict__ sbd) {
  __shared__ unsigned long long kt[256];
  int b = blockIdx.y;
  int i = blockIdx.x * 256 + threadIdx.x;
  bool act = i < NLOC;
  unsigned long long ki = act ? ukey[(size_t)b * NLOC + i] : ~0ull;
  int cnt = 0;
  for (int t = 0; t < 88; ++t) {
    int j0 = t * 256;
    int j = j0 + threadIdx.x;
    kt[threadIdx.x] = (j < NLOC) ? ukey[(size_t)b * NLOC + j] : ~0ull;
    __syncthreads();
#pragma unroll 8
    for (int jj = 0; jj < 256; ++jj) {
      unsigned long long kj = kt[jj];
      int jidx = j0 + jj;
      // better than i: smaller key, or equal key with smaller index.
      cnt += ((kj < ki) || (kj == ki && jidx < i)) ? 1 : 0;
    }
    __syncthreads();
  }
  if (act && cnt < NPRE) {
    const double* bx = &boxd[((size_t)b * NLOC + i) * 4];
    double* dp = &sbd[((size_t)b * NPRE + cnt) * 4];
    dp[0] = bx[0]; dp[1] = bx[1]; dp[2] = bx[2]; dp[3] = bx[3];
  }
}

// ---------------- kernel 5: NMS suppression bitmask matrix (f64 IoU) ----------------
__global__ __launch_bounds__(64) void nmsmask_kernel(
    const double* __restrict__ sbd, unsigned long long* __restrict__ M) {
  __shared__ double cb[64][4];
  int b = blockIdx.z;
  int jw = blockIdx.y;
  int i  = blockIdx.x * 64 + threadIdx.x;
  int j  = jw * 64 + threadIdx.x;
  double j0 = 0, j1 = 0, j2 = 0, j3 = 0;
  if (j < NPRE) {
    const double* bp = &sbd[((size_t)b * NPRE + j) * 4];
    j0 = bp[0]; j1 = bp[1]; j2 = bp[2]; j3 = bp[3];
  }
  cb[threadIdx.x][0] = j0; cb[threadIdx.x][1] = j1;
  cb[threadIdx.x][2] = j2; cb[threadIdx.x][3] = j3;
  __syncthreads();
  if (i >= NPRE) return;
  const double* bp = &sbd[((size_t)b * NPRE + i) * 4];
  double i0 = bp[0], i1 = bp[1], i2 = bp[2], i3 = bp[3];
  double ai = (i2 - i0) * (i3 - i1);
  unsigned long long mask = 0ull;
#pragma unroll 4
  for (int t = 0; t < 64; ++t) {
    double aj = (cb[t][2] - cb[t][0]) * (cb[t][3] - cb[t][1]);
    double h = fmax(fmin(i2, cb[t][2]) - fmax(i0, cb[t][0]), 0.0);
    double w = fmax(fmin(i3, cb[t][3]) - fmax(i1, cb[t][1]), 0.0);
    double inter = h * w;
    double iou = inter / (ai + aj - inter + 1e-9);
    mask |= ((iou > 0.7) ? 1ull : 0ull) << t;
  }
  M[((size_t)b * ROWPAD + i) * WSTRIDE + jw] = mask;
}

// ---------------- kernel 6: sequential NMS scan (1 wave / image) ----------------
__global__ __launch_bounds__(64) void nms_scan_kernel(
    const double* __restrict__ sbd, const unsigned long long* __restrict__ M,
    float* __restrict__ d_out) {
  int b = blockIdx.x;
  int lane = threadIdx.x;
  for (int k = lane; k < NPOST; k += 64) {
    *(float4*)&d_out[ROIS_OFF + (size_t)(b * NPOST + k) * 4] = make_float4(0, 0, 0, 0);
    d_out[IDX_OFF + b * NPOST + k] = (float)b;
  }
  __syncthreads();

  unsigned long long R = ~0ull;
  if (lane < WORDS) R = 0ull;
  for (int w = 0; w < WORDS; ++w) {
    int j = w * 64 + lane;
    bool inval = true;
    if (j < NPRE) {
      const double* bp = &sbd[((size_t)b * NPRE + j) * 4];
      double h = bp[2] - bp[0], wd = bp[3] - bp[1];
      inval = !(h >= 16.0 && wd >= 16.0);
    }
    unsigned long long bal = __ballot(inval ? 1 : 0);
    if (lane == w) R |= bal;
  }

  int kept = 0;
  while (kept < NPOST) {
    unsigned long long hz = __ballot(((~R) != 0ull) ? 1 : 0);
    if (hz == 0ull) break;
    int w0 = __ffsll(hz) - 1;
    unsigned long long word = __shfl(R, w0);
    int bit = __ffsll(~word) - 1;
    int i = w0 * 64 + bit;
    if (lane < 4)
      d_out[ROIS_OFF + (size_t)(b * NPOST + kept) * 4 + lane] =
          (float)sbd[((size_t)b * NPRE + i) * 4 + lane];
    kept++;
    if (kept >= NPOST) break;
    unsigned long long row = (lane < WORDS)
        ? M[((size_t)b * ROWPAD + i) * WSTRIDE + lane] : 0ull;
    R |= row;
    if (lane == w0) R |= (1ull << bit);
  }
}

// ---------------- launch ----------------
extern "C" void kernel_launch(void* const* d_in, const int* in_sizes, int n_in,
                              void* d_out, int out_size, void* d_ws, size_t ws_size,
                              hipStream_t stream) {
  const float* in     = (const float*)d_in[0];
  const float* conv_w = (const float*)d_in[1];
  const float* conv_b = (const float*)d_in[2];
  const float* bf_w   = (const float*)d_in[3];
  const float* bf_b   = (const float*)d_in[4];
  const float* loc_w  = (const float*)d_in[5];
  const float* loc_b  = (const float*)d_in[6];
  const int*   imh    = (const int*)d_in[7];
  const int*   imw    = (const int*)d_in[8];
  float* out = (float*)d_out;

  char* ws = (char*)d_ws;
  float*  Wt    = (float*)(ws + WS_WT);
  double* rawd  = (double*)(ws + WS_WT);     // aliases Wt (dead after conv3x3)
  float*  W1t   = (float*)(ws + WS_W1T);
  float*  feat  = (float*)(ws + WS_FEAT);
  unsigned long long* ukey = (unsigned long long*)(ws + WS_SCORE);
  double* boxd  = (double*)(ws + WS_BOXD);
  double* sbd   = (double*)(ws + WS_SBD);
  unsigned long long* M = (unsigned long long*)(ws + WS_M);

  hipLaunchKernelGGL(prep_kernel, dim3((4608 * 512 + 512 * 64 + 255) / 256), dim3(256),
                     0, stream, conv_w, loc_w, bf_w, Wt, W1t);
  hipLaunchKernelGGL(conv3x3_kernel, dim3(79, 16), dim3(256), 0, stream,
                     in, Wt, conv_b, feat);
  hipLaunchKernelGGL(conv1x1_kernel, dim3(79), dim3(256), 0, stream,
                     feat, W1t, loc_b, bf_b, rawd);
  hipLaunchKernelGGL(epilogue_kernel, dim3((BIMG * NLOC + 255) / 256), dim3(256), 0, stream,
                     rawd, out, boxd, ukey, imh, imw);
  hipLaunchKernelGGL(select_kernel, dim3(88, 4), dim3(256), 0, stream,
                     ukey, boxd, sbd);
  hipLaunchKernelGGL(nmsmask_kernel, dim3(47, 47, 4), dim3(64), 0, stream, sbd, M);
  hipLaunchKernelGGL(nms_scan_kernel, dim3(4), dim3(64), 0, stream, sbd, M, out);
}